// Round 7
// baseline (4175.547 us; speedup 1.0000x reference)
//
#include <hip/hip_runtime.h>

// ---------------------------------------------------------------------------
// 2-layer LSTM, T=1024, B=32, D=256, H=512. Inputs fp32, OUTPUT fp32.
//   pack_w3: fp32 {W_hh0, W_hh1, W_ih1} -> bf16 MFMA B-fragment order.
//   gemm_xp: xp0 = x @ W_ih0^T (bf16 MFMA).
//   lstm_pipe3: persistent 96-wg x 256-thr kernel, 3 stages of 32 wgs:
//     role0 L0 : layer0 recurrence (fan-in-32 flag barrier), writes hs0[t]
//                slots (write-once) + own double buffer.
//     role1 XP1: stateless xp1[t] = hs0[t] @ Wih1^T. Ring depth 4,
//                backpressure on fL1[t-4].
//     role2 L1 : layer1 recurrence + fan-in-1 poll of its XP1 wg + 4 direct
//                xp word loads.
//   All exchange via proven fence-free relaxed agent atomics.
//
// R13: baseline + PIPELINED FLAG POLLING (poll6). The naive dependent-load
// spin quantizes flag discovery to a full MALL RT (~600-1000 cyc); keeping 6
// loads in flight cuts that to ~RT/6. Single-variable experiment: protocol,
// ordering, and layout are byte-identical to the 3528-3559 us baseline.
// Pre-committed read: neutral result => discovery quantization is not the
// gap; the ~3.4 us step is store-visibility + load RT + compute = floor.
// ---------------------------------------------------------------------------

typedef __bf16 bf16x8 __attribute__((ext_vector_type(8)));
typedef float  f32x4  __attribute__((ext_vector_type(4)));
typedef float  f32x2  __attribute__((ext_vector_type(2)));
typedef unsigned long long u64;
typedef unsigned int u32;

#define MFMA16(a, b, c) __builtin_amdgcn_mfma_f32_16x16x32_bf16((a), (b), (c), 0, 0, 0)
#define SCOPE_AGENT __HIP_MEMORY_SCOPE_AGENT

__device__ __forceinline__ float fsigm(float x) { return 1.0f / (1.0f + __expf(-x)); }
__device__ __forceinline__ float ftanh(float x) {
    x = fminf(15.0f, fmaxf(-15.0f, x));
    float e = __expf(2.0f * x);
    return (e - 1.0f) / (e + 1.0f);
}

__device__ __forceinline__ bf16x8 frag_from(u64 lo, u64 hi) {
    union { u64 u[2]; bf16x8 v; } x;
    x.u[0] = lo; x.u[1] = hi;
    return x.v;
}

// Pipelined flag poll: 6 relaxed agent loads in flight to the same address
// (atomics are never CSE'd), checked oldest-first. Poll arrival density at
// the MALL ~RT/6 instead of ~RT, so discovery of the flag flip costs
// ~lambda + RT/6 instead of ~lambda + U(0,RT).
__device__ __forceinline__ void poll6(const int* __restrict__ p) {
    u32 v0 = (u32)__hip_atomic_load(p, __ATOMIC_RELAXED, SCOPE_AGENT);
    u32 v1 = (u32)__hip_atomic_load(p, __ATOMIC_RELAXED, SCOPE_AGENT);
    u32 v2 = (u32)__hip_atomic_load(p, __ATOMIC_RELAXED, SCOPE_AGENT);
    u32 v3 = (u32)__hip_atomic_load(p, __ATOMIC_RELAXED, SCOPE_AGENT);
    u32 v4 = (u32)__hip_atomic_load(p, __ATOMIC_RELAXED, SCOPE_AGENT);
    u32 v5 = (u32)__hip_atomic_load(p, __ATOMIC_RELAXED, SCOPE_AGENT);
    while (v0 == 0) {
        v0 = v1; v1 = v2; v2 = v3; v3 = v4; v4 = v5;
        v5 = (u32)__hip_atomic_load(p, __ATOMIC_RELAXED, SCOPE_AGENT);
    }
}

// ---------------------------------------------------------------------------
// Pack [2048][512] fp32 -> per-(wg,wave,ktile) bf16 B-fragment order:
//   WB[((w*4+v)*16+kk)*512 + lane*8 + e] = bf16(W[grow][k0+e])
//   n = v*16+(lane&15); grow = (n>>4)*512 + w*16 + (n&15); k0 = kk*32+(lane>>4)*8
// wg w owns h-cols [w*16, w*16+16) for all 4 gates.
// ---------------------------------------------------------------------------
__global__ void pack_w3(const float* __restrict__ W0, const float* __restrict__ W1,
                        const float* __restrict__ W2, __bf16* __restrict__ O0,
                        __bf16* __restrict__ O1, __bf16* __restrict__ O2) {
    int gtid = blockIdx.x * 256 + threadIdx.x;          // 0 .. 393215
    int sel  = gtid >> 17;                              // 0,1,2
    const float* W = (sel == 0) ? W0 : (sel == 1) ? W1 : W2;
    __bf16* WB     = (sel == 0) ? O0 : (sel == 1) ? O1 : O2;
    int tid  = gtid & 131071;
    int lane = tid & 63;
    int kk   = (tid >> 6) & 15;
    int v    = (tid >> 10) & 3;
    int w    = tid >> 12;                               // 0..31
    int n    = v * 16 + (lane & 15);
    int grow = (n >> 4) * 512 + w * 16 + (n & 15);
    int k0   = kk * 32 + (lane >> 4) * 8;
    const float* src = W + (size_t)grow * 512 + k0;
    bf16x8 val;
#pragma unroll
    for (int e = 0; e < 8; e++) val[e] = (__bf16)src[e];
    *(bf16x8*)(WB + (size_t)tid * 8) = val;
}

// ---------------------------------------------------------------------------
// xp0[r][n] = sum_k x_perm(r)[k] * W[n][k], r = t*32+b, x is [B,T,D] fp32.
// ---------------------------------------------------------------------------
__global__ __launch_bounds__(256, 2) void gemm_xp(const float* __restrict__ A,
                                                  const float* __restrict__ W,
                                                  __bf16* __restrict__ out, int K) {
    const int tid = threadIdx.x, lane = tid & 63, wv = tid >> 6;
    const int bm = blockIdx.x >> 4, bn = blockIdx.x & 15;
    const int m_base = bm * 128 + (wv & 1) * 64;
    const int n_base = bn * 128 + (wv >> 1) * 64;
    const int kq = (lane >> 4) * 8;
    const int rl = lane & 15;

    f32x4 acc[4][4];
#pragma unroll
    for (int i = 0; i < 4; i++)
#pragma unroll
        for (int j = 0; j < 4; j++) acc[i][j] = (f32x4){0.f, 0.f, 0.f, 0.f};

    const int nk = K >> 5;
    for (int kk = 0; kk < nk; kk++) {
        int k0 = kk * 32 + kq;
        bf16x8 af[4], bfr[4];
#pragma unroll
        for (int mt = 0; mt < 4; mt++) {
            int row = m_base + mt * 16 + rl;
            const float* ap = A + (size_t)((row & 31) * 1024 + (row >> 5)) * K + k0;
#pragma unroll
            for (int e = 0; e < 8; e++) af[mt][e] = (__bf16)ap[e];
        }
#pragma unroll
        for (int nt = 0; nt < 4; nt++) {
            int n = n_base + nt * 16 + rl;
            const float* wp = W + (size_t)n * K + k0;
#pragma unroll
            for (int e = 0; e < 8; e++) bfr[nt][e] = (__bf16)wp[e];
        }
#pragma unroll
        for (int mt = 0; mt < 4; mt++)
#pragma unroll
            for (int nt = 0; nt < 4; nt++)
                acc[mt][nt] = MFMA16(af[mt], bfr[nt], acc[mt][nt]);
    }

    const int rq = (lane >> 4) * 4;
#pragma unroll
    for (int mt = 0; mt < 4; mt++)
#pragma unroll
        for (int nt = 0; nt < 4; nt++)
#pragma unroll
            for (int r = 0; r < 4; r++) {
                int row = m_base + mt * 16 + rq + r;
                int col = n_base + nt * 16 + rl;
                out[(size_t)row * 2048 + col] = (__bf16)acc[mt][nt][r];
            }
}

// ---------------------------------------------------------------------------
// 3-stage pipelined recurrence. 96 wgs x 256. role = blockIdx/32, w = %32.
// wg w (any role) owns h-cols [w*16, w*16+16) x 4 gates.
// ---------------------------------------------------------------------------
__global__ __launch_bounds__(256, 1) void lstm_pipe3(
    const __bf16* __restrict__ xp0,    // [32768][2048] bf16, row = t*32+b
    const __bf16* __restrict__ WB0,    // W_hh0 packed
    const __bf16* __restrict__ WBw1,   // W_hh1 packed
    const __bf16* __restrict__ WBi1,   // W_ih1 packed
    const float* __restrict__ bias0,
    const float* __restrict__ bias1,
    __bf16* __restrict__ hbuf0,        // [2][32][512] zeroed
    __bf16* __restrict__ hbuf1,        // [2][32][512] zeroed
    __bf16* __restrict__ hs0s,         // [1024][32][512] write-once slots
    __bf16* __restrict__ xp1r,         // [4][32][2048] ring
    float* __restrict__ out_f32,       // [32][1024][512]
    float* __restrict__ hn_out,        // [2][32][512]
    float* __restrict__ cn_out,        // [2][32][512]
    int* __restrict__ fL0,             // [32][1024] zeroed, stride 1024
    int* __restrict__ fX,              // [32][1024] zeroed
    int* __restrict__ fL1) {           // [32][1024] zeroed
    const int tid  = threadIdx.x;
    const int role = blockIdx.x >> 5;   // 0=L0, 1=XP1, 2=L1
    const int w    = blockIdx.x & 31;
    const int lane = tid & 63;
    const int wv   = tid >> 6;

    __shared__ __bf16 h_lds[32 * 516];  // staged state (stride 516)
    __shared__ float  g_lds[32 * 68];   // gates [32 b][64 cols +4]

    // --- weights resident in registers (64 VGPRs/lane) ---
    bf16x8 wreg[16];
    {
        const __bf16* WB = (role == 0) ? WB0 : (role == 1) ? WBi1 : WBw1;
        const __bf16* wb = WB + (size_t)(w * 4 + wv) * 16 * 512 + lane * 8;
#pragma unroll
        for (int kk = 0; kk < 16; kk++) wreg[kk] = *(const bf16x8*)(wb + kk * 512);
    }

    // --- elementwise mapping: thread -> (b, j0, j0+1) ---
    const int b  = tid >> 3;
    const int jp = tid & 7;
    const int j0 = w * 16 + jp * 2;
    const int arow = lane & 15;
    const int kq8  = (lane >> 4) * 8;

    f32x2 bsv[4];
    if (role != 1) {
        const float* bias = (role == 0) ? bias0 : bias1;
#pragma unroll
        for (int g = 0; g < 4; g++) bsv[g] = *(const f32x2*)(bias + g * 512 + j0);
    }
    float cc0 = 0.f, cc1 = 0.f;

    __bf16* hbuf = (role == 0) ? hbuf0 : hbuf1;   // recurrent double buffer
    int* fMy = (role == 0) ? fL0 : (role == 1) ? fX : fL1;

    // xp0 prefetch (role 0 only)
    u32 xc[4] = {0, 0, 0, 0}, xn[4] = {0, 0, 0, 0};
    if (role == 0) {
#pragma unroll
        for (int g = 0; g < 4; g++)
            xc[g] = *(const u32*)(xp0 + (size_t)b * 2048 + g * 512 + j0);
    }

    for (int t = 0; t < 1024; t++) {
        // ---------------- top-of-step wait (pipelined polls) ----------------
        if (role == 0) {
            int tn = (t < 1023) ? t + 1 : 1023;
#pragma unroll
            for (int g = 0; g < 4; g++)
                xn[g] = *(const u32*)(xp0 + (size_t)(tn * 32 + b) * 2048 + g * 512 + j0);
            if (t > 0) {
                if (tid < 32)
                    poll6(&fL0[tid * 1024 + t - 1]);
                asm volatile("" ::: "memory");
                __syncthreads();
            }
        } else if (role == 1) {
            if (tid < 32)
                poll6(&fL0[tid * 1024 + t]);
            else if (tid == 32 && t >= 4)
                while (__hip_atomic_load(&fL1[w * 1024 + t - 4], __ATOMIC_RELAXED,
                                         SCOPE_AGENT) == 0) {}
            asm volatile("" ::: "memory");
            __syncthreads();
        } else {
            if (tid < 32) {
                if (t > 0)
                    poll6(&fL1[tid * 1024 + t - 1]);
            } else if (tid == 32) {
                poll6(&fX[w * 1024 + t]);
            }
            asm volatile("" ::: "memory");
            __syncthreads();
        }

        // ---------------- stage state into LDS ----------------
        // role0: hbuf0[t&1]; role1: hs0s[t]; role2: xp words + hbuf1[t&1]
        u32 xpr[4];
        if (role == 2) {
            const __bf16* xs = xp1r + (size_t)(t & 3) * 65536 + (size_t)b * 2048 + j0;
#pragma unroll
            for (int g = 0; g < 4; g++)
                xpr[g] = __hip_atomic_load((const u32*)(xs + g * 512),
                                           __ATOMIC_RELAXED, SCOPE_AGENT);
        }
        {
            const u64* hg = (role == 1)
                ? (const u64*)(hs0s + (size_t)t * 16384)
                : (const u64*)(hbuf + (size_t)(t & 1) * 16384);
            u64 hv[16];
#pragma unroll
            for (int i = 0; i < 16; i++)
                hv[i] = __hip_atomic_load(hg + i * 256 + tid, __ATOMIC_RELAXED, SCOPE_AGENT);
#pragma unroll
            for (int i = 0; i < 16; i++) {
                int f  = (i * 256 + tid) * 4;
                int br = f >> 9, col = f & 511;
                *(u64*)(h_lds + br * 516 + col) = hv[i];
            }
        }
        __syncthreads();

        // ---------------- 32 MFMAs ----------------
        f32x4 acc0 = (f32x4){0.f, 0.f, 0.f, 0.f};
        f32x4 acc1 = (f32x4){0.f, 0.f, 0.f, 0.f};
#pragma unroll
        for (int kk = 0; kk < 16; kk++) {
            const __bf16* p0 = h_lds + arow * 516 + kq8 + kk * 32;
            const __bf16* p1 = p0 + 16 * 516;
            bf16x8 a0 = frag_from(*(const u64*)p0, *(const u64*)(p0 + 4));
            bf16x8 a1 = frag_from(*(const u64*)p1, *(const u64*)(p1 + 4));
            acc0 = MFMA16(a0, wreg[kk], acc0);
            acc1 = MFMA16(a1, wreg[kk], acc1);
        }
        {
            int col   = wv * 16 + (lane & 15);
            int rbase = (lane >> 4) * 4;
#pragma unroll
            for (int r = 0; r < 4; r++) {
                g_lds[(rbase + r) * 68 + col]      = acc0[r];
                g_lds[(16 + rbase + r) * 68 + col] = acc1[r];
            }
        }
        __syncthreads();

        // ---------------- per-role epilogue ----------------
        if (role == 1) {
            // pack projection to bf16, store to ring, flag
            const float* gl = g_lds + b * 68 + jp * 2;
            __bf16* xd = xp1r + (size_t)(t & 3) * 65536 + (size_t)b * 2048 + j0;
#pragma unroll
            for (int g = 0; g < 4; g++) {
                f32x2 gv = *(const f32x2*)(gl + g * 16);
                union { __bf16 v2[2]; u32 u; } pu;
                pu.v2[0] = (__bf16)gv[0]; pu.v2[1] = (__bf16)gv[1];
                __hip_atomic_store((u32*)(xd + g * 512), pu.u,
                                   __ATOMIC_RELAXED, SCOPE_AGENT);
            }
            asm volatile("s_waitcnt vmcnt(0)" ::: "memory");
            __syncthreads();
            if (tid == 0)
                __hip_atomic_store(&fX[w * 1024 + t], 1, __ATOMIC_RELAXED, SCOPE_AGENT);
        } else {
            float hf0, hf1;
            {
                u32 x0 = (role == 0) ? xc[0] : xpr[0];
                u32 x1 = (role == 0) ? xc[1] : xpr[1];
                u32 x2 = (role == 0) ? xc[2] : xpr[2];
                u32 x3 = (role == 0) ? xc[3] : xpr[3];
                union { u32 u; __bf16 v2[2]; } xi, xf, xg, xo;
                xi.u = x0; xf.u = x1; xg.u = x2; xo.u = x3;
                const float* gl = g_lds + b * 68 + jp * 2;
                f32x2 gi = *(const f32x2*)(gl);
                f32x2 gf = *(const f32x2*)(gl + 16);
                f32x2 gg = *(const f32x2*)(gl + 32);
                f32x2 go = *(const f32x2*)(gl + 48);

                float i0 = fsigm(gi[0] + (float)xi.v2[0] + bsv[0][0]);
                float f0 = fsigm(gf[0] + (float)xf.v2[0] + bsv[1][0]);
                float g0 = ftanh(gg[0] + (float)xg.v2[0] + bsv[2][0]);
                float o0 = fsigm(go[0] + (float)xo.v2[0] + bsv[3][0]);
                cc0 = f0 * cc0 + i0 * g0;
                hf0 = o0 * ftanh(cc0);

                float i1 = fsigm(gi[1] + (float)xi.v2[1] + bsv[0][1]);
                float f1 = fsigm(gf[1] + (float)xf.v2[1] + bsv[1][1]);
                float g1 = ftanh(gg[1] + (float)xg.v2[1] + bsv[2][1]);
                float o1 = fsigm(go[1] + (float)xo.v2[1] + bsv[3][1]);
                cc1 = f1 * cc1 + i1 * g1;
                hf1 = o1 * ftanh(cc1);
            }
            union { __bf16 v2[2]; u32 u; } hu;
            hu.v2[0] = (__bf16)hf0; hu.v2[1] = (__bf16)hf1;

            // recurrent state store (+ hs0 slot for role 0)
            __hip_atomic_store((u32*)(hbuf + (size_t)((t + 1) & 1) * 16384 +
                                      (size_t)b * 512 + j0),
                               hu.u, __ATOMIC_RELAXED, SCOPE_AGENT);
            if (role == 0)
                __hip_atomic_store((u32*)(hs0s + ((size_t)t * 32 + b) * 512 + j0), hu.u,
                                   __ATOMIC_RELAXED, SCOPE_AGENT);
            asm volatile("s_waitcnt vmcnt(0)" ::: "memory");
            __syncthreads();
            if (tid == 0)
                __hip_atomic_store(&fMy[w * 1024 + t], 1, __ATOMIC_RELAXED, SCOPE_AGENT);

            // non-critical stores overlap flag propagation
            if (role == 2)
                *(f32x2*)(out_f32 + (size_t)b * 524288 + (size_t)t * 512 + j0) =
                    (f32x2){hf0, hf1};
            if (t == 1023) {
                int li = (role == 0) ? 0 : 1;
                *(f32x2*)(hn_out + (size_t)li * 16384 + (size_t)b * 512 + j0) =
                    (f32x2){hf0, hf1};
                *(f32x2*)(cn_out + (size_t)li * 16384 + (size_t)b * 512 + j0) =
                    (f32x2){cc0, cc1};
            }
#pragma unroll
            for (int g = 0; g < 4; g++) xc[g] = xn[g];
        }
    }
}

// ---------------------------------------------------------------------------
extern "C" void kernel_launch(void* const* d_in, const int* in_sizes, int n_in,
                              void* d_out, int out_size, void* d_ws, size_t ws_size,
                              hipStream_t stream) {
    (void)in_sizes; (void)n_in; (void)out_size; (void)ws_size;
    const float* x    = (const float*)d_in[0];  // [32][1024][256] fp32
    const float* Wih0 = (const float*)d_in[1];  // [2048][256] fp32
    const float* b0   = (const float*)d_in[2];  // [2048] fp32
    const float* Whh0 = (const float*)d_in[3];  // [2048][512] fp32
    const float* Wih1 = (const float*)d_in[4];  // [2048][512] fp32
    const float* b1   = (const float*)d_in[5];  // [2048] fp32
    const float* Whh1 = (const float*)d_in[6];  // [2048][512] fp32
    float* dout = (float*)d_out;  // fp32: out(16777216) | h_n(2*16384) | c_n(2*16384)

    char* wsb = (char*)d_ws;
    int*    fL0   = (int*)wsb;                                  // 128 KB
    int*    fX    = (int*)(wsb + (128 << 10));                  // 128 KB
    int*    fL1   = (int*)(wsb + (256 << 10));                  // 128 KB
    __bf16* hbuf0 = (__bf16*)(wsb + (384 << 10));               // 64 KB
    __bf16* hbuf1 = (__bf16*)(wsb + (448 << 10));               // 64 KB
    __bf16* WB0   = (__bf16*)(wsb + (512 << 10));               // 2 MB
    __bf16* WBw1  = (__bf16*)(wsb + (512 << 10) + (2 << 20));   // 2 MB
    __bf16* WBi1  = (__bf16*)(wsb + (512 << 10) + (4 << 20));   // 2 MB
    __bf16* xp1r  = (__bf16*)(wsb + (512 << 10) + (6 << 20));   // 512 KB
    __bf16* hs0s  = (__bf16*)(wsb + (1 << 20) + (7 << 20));     // 32 MB
    __bf16* xpb   = (__bf16*)(wsb + (40 << 20));                // 128 MB

    // zero flags + both h double-buffers (contiguous 512 KB)
    (void)hipMemsetAsync(wsb, 0, 512 << 10, stream);

    pack_w3<<<dim3(1536), dim3(256), 0, stream>>>(Whh0, Whh1, Wih1, WB0, WBw1, WBi1);

    // xp0 = x @ Wih0^T  (K=256, fp32 A, permuted rows)
    gemm_xp<<<dim3(4096), dim3(256), 0, stream>>>(x, Wih0, xpb, 256);

    lstm_pipe3<<<dim3(96), dim3(256), 0, stream>>>(
        xpb, WB0, WBw1, WBi1, b0, b1, hbuf0, hbuf1, hs0s, xp1r,
        dout, dout + 16777216, dout + 16777216 + 32768, fL0, fX, fL1);
}

// Round 8
// 3866.618 us; speedup vs baseline: 1.0799x; 1.0799x over previous
//
#include <hip/hip_runtime.h>

// ---------------------------------------------------------------------------
// 2-layer LSTM, T=1024, B=32, D=256, H=512. Inputs fp32, OUTPUT fp32.
//   pack_w3: fp32 {W_hh0, W_hh1, W_ih1} -> bf16 MFMA B-fragment order.
//   gemm_xp: xp0 = x @ W_ih0^T (bf16 MFMA).
//   lstm_pipe3: persistent 96-wg x 256-thr kernel, 3 stages of 32 wgs:
//     role0 L0 : layer0 recurrence (fan-in-32 flag barrier), writes hs0[t]
//                slots (write-once) + own double buffer.
//     role1 XP1: stateless xp1[t] = hs0[t] @ Wih1^T. Ring depth 4,
//                backpressure on fL1[t-4].
//     role2 L1 : layer1 recurrence + fan-in-1 poll of its XP1 wg + 4 direct
//                xp word loads.
//   All exchange via proven fence-free relaxed agent atomics.
//
// R14 FINAL (session verdict): baseline restored. Six exchange protocols
// were tested across R7-R13 (self-validating pairs 3693, fused 2-stage 7748,
// selective-retry pairs 4405, chunk-pipelined 7900, pipelined flag poll
// 3846 vs baseline 3528-3559 us). Both directions of the design space
// (fewer protocol hops <-> denser polling) regress: removed hops re-appear
// as poll/retry MALL traffic, denser polling slows the very store
// visibility it waits on. The ~3.4 us/step is store-visibility + flag hop +
// data RT + ~1500 cyc compute on a serial dependence chain through the
// MALL — a latency floor not visible as a counter roofline (HBM ~4.5%,
// MfmaUtil ~2.3%). Cross-XCD latency is not reducible at HIP level without
// illegal wg->XCD placement assumptions (G16).
// ---------------------------------------------------------------------------

typedef __bf16 bf16x8 __attribute__((ext_vector_type(8)));
typedef float  f32x4  __attribute__((ext_vector_type(4)));
typedef float  f32x2  __attribute__((ext_vector_type(2)));
typedef unsigned long long u64;
typedef unsigned int u32;

#define MFMA16(a, b, c) __builtin_amdgcn_mfma_f32_16x16x32_bf16((a), (b), (c), 0, 0, 0)
#define SCOPE_AGENT __HIP_MEMORY_SCOPE_AGENT

__device__ __forceinline__ float fsigm(float x) { return 1.0f / (1.0f + __expf(-x)); }
__device__ __forceinline__ float ftanh(float x) {
    x = fminf(15.0f, fmaxf(-15.0f, x));
    float e = __expf(2.0f * x);
    return (e - 1.0f) / (e + 1.0f);
}

__device__ __forceinline__ bf16x8 frag_from(u64 lo, u64 hi) {
    union { u64 u[2]; bf16x8 v; } x;
    x.u[0] = lo; x.u[1] = hi;
    return x.v;
}

// ---------------------------------------------------------------------------
// Pack [2048][512] fp32 -> per-(wg,wave,ktile) bf16 B-fragment order:
//   WB[((w*4+v)*16+kk)*512 + lane*8 + e] = bf16(W[grow][k0+e])
//   n = v*16+(lane&15); grow = (n>>4)*512 + w*16 + (n&15); k0 = kk*32+(lane>>4)*8
// wg w owns h-cols [w*16, w*16+16) for all 4 gates.
// ---------------------------------------------------------------------------
__global__ void pack_w3(const float* __restrict__ W0, const float* __restrict__ W1,
                        const float* __restrict__ W2, __bf16* __restrict__ O0,
                        __bf16* __restrict__ O1, __bf16* __restrict__ O2) {
    int gtid = blockIdx.x * 256 + threadIdx.x;          // 0 .. 393215
    int sel  = gtid >> 17;                              // 0,1,2
    const float* W = (sel == 0) ? W0 : (sel == 1) ? W1 : W2;
    __bf16* WB     = (sel == 0) ? O0 : (sel == 1) ? O1 : O2;
    int tid  = gtid & 131071;
    int lane = tid & 63;
    int kk   = (tid >> 6) & 15;
    int v    = (tid >> 10) & 3;
    int w    = tid >> 12;                               // 0..31
    int n    = v * 16 + (lane & 15);
    int grow = (n >> 4) * 512 + w * 16 + (n & 15);
    int k0   = kk * 32 + (lane >> 4) * 8;
    const float* src = W + (size_t)grow * 512 + k0;
    bf16x8 val;
#pragma unroll
    for (int e = 0; e < 8; e++) val[e] = (__bf16)src[e];
    *(bf16x8*)(WB + (size_t)tid * 8) = val;
}

// ---------------------------------------------------------------------------
// xp0[r][n] = sum_k x_perm(r)[k] * W[n][k], r = t*32+b, x is [B,T,D] fp32.
// ---------------------------------------------------------------------------
__global__ __launch_bounds__(256, 2) void gemm_xp(const float* __restrict__ A,
                                                  const float* __restrict__ W,
                                                  __bf16* __restrict__ out, int K) {
    const int tid = threadIdx.x, lane = tid & 63, wv = tid >> 6;
    const int bm = blockIdx.x >> 4, bn = blockIdx.x & 15;
    const int m_base = bm * 128 + (wv & 1) * 64;
    const int n_base = bn * 128 + (wv >> 1) * 64;
    const int kq = (lane >> 4) * 8;
    const int rl = lane & 15;

    f32x4 acc[4][4];
#pragma unroll
    for (int i = 0; i < 4; i++)
#pragma unroll
        for (int j = 0; j < 4; j++) acc[i][j] = (f32x4){0.f, 0.f, 0.f, 0.f};

    const int nk = K >> 5;
    for (int kk = 0; kk < nk; kk++) {
        int k0 = kk * 32 + kq;
        bf16x8 af[4], bfr[4];
#pragma unroll
        for (int mt = 0; mt < 4; mt++) {
            int row = m_base + mt * 16 + rl;
            const float* ap = A + (size_t)((row & 31) * 1024 + (row >> 5)) * K + k0;
#pragma unroll
            for (int e = 0; e < 8; e++) af[mt][e] = (__bf16)ap[e];
        }
#pragma unroll
        for (int nt = 0; nt < 4; nt++) {
            int n = n_base + nt * 16 + rl;
            const float* wp = W + (size_t)n * K + k0;
#pragma unroll
            for (int e = 0; e < 8; e++) bfr[nt][e] = (__bf16)wp[e];
        }
#pragma unroll
        for (int mt = 0; mt < 4; mt++)
#pragma unroll
            for (int nt = 0; nt < 4; nt++)
                acc[mt][nt] = MFMA16(af[mt], bfr[nt], acc[mt][nt]);
    }

    const int rq = (lane >> 4) * 4;
#pragma unroll
    for (int mt = 0; mt < 4; mt++)
#pragma unroll
        for (int nt = 0; nt < 4; nt++)
#pragma unroll
            for (int r = 0; r < 4; r++) {
                int row = m_base + mt * 16 + rq + r;
                int col = n_base + nt * 16 + rl;
                out[(size_t)row * 2048 + col] = (__bf16)acc[mt][nt][r];
            }
}

// ---------------------------------------------------------------------------
// 3-stage pipelined recurrence. 96 wgs x 256. role = blockIdx/32, w = %32.
// wg w (any role) owns h-cols [w*16, w*16+16) x 4 gates.
// ---------------------------------------------------------------------------
__global__ __launch_bounds__(256, 1) void lstm_pipe3(
    const __bf16* __restrict__ xp0,    // [32768][2048] bf16, row = t*32+b
    const __bf16* __restrict__ WB0,    // W_hh0 packed
    const __bf16* __restrict__ WBw1,   // W_hh1 packed
    const __bf16* __restrict__ WBi1,   // W_ih1 packed
    const float* __restrict__ bias0,
    const float* __restrict__ bias1,
    __bf16* __restrict__ hbuf0,        // [2][32][512] zeroed
    __bf16* __restrict__ hbuf1,        // [2][32][512] zeroed
    __bf16* __restrict__ hs0s,         // [1024][32][512] write-once slots
    __bf16* __restrict__ xp1r,         // [4][32][2048] ring
    float* __restrict__ out_f32,       // [32][1024][512]
    float* __restrict__ hn_out,        // [2][32][512]
    float* __restrict__ cn_out,        // [2][32][512]
    int* __restrict__ fL0,             // [32][1024] zeroed, stride 1024
    int* __restrict__ fX,              // [32][1024] zeroed
    int* __restrict__ fL1) {           // [32][1024] zeroed
    const int tid  = threadIdx.x;
    const int role = blockIdx.x >> 5;   // 0=L0, 1=XP1, 2=L1
    const int w    = blockIdx.x & 31;
    const int lane = tid & 63;
    const int wv   = tid >> 6;

    __shared__ __bf16 h_lds[32 * 516];  // staged state (stride 516)
    __shared__ float  g_lds[32 * 68];   // gates [32 b][64 cols +4]

    // --- weights resident in registers (64 VGPRs/lane) ---
    bf16x8 wreg[16];
    {
        const __bf16* WB = (role == 0) ? WB0 : (role == 1) ? WBi1 : WBw1;
        const __bf16* wb = WB + (size_t)(w * 4 + wv) * 16 * 512 + lane * 8;
#pragma unroll
        for (int kk = 0; kk < 16; kk++) wreg[kk] = *(const bf16x8*)(wb + kk * 512);
    }

    // --- elementwise mapping: thread -> (b, j0, j0+1) ---
    const int b  = tid >> 3;
    const int jp = tid & 7;
    const int j0 = w * 16 + jp * 2;
    const int arow = lane & 15;
    const int kq8  = (lane >> 4) * 8;

    f32x2 bsv[4];
    if (role != 1) {
        const float* bias = (role == 0) ? bias0 : bias1;
#pragma unroll
        for (int g = 0; g < 4; g++) bsv[g] = *(const f32x2*)(bias + g * 512 + j0);
    }
    float cc0 = 0.f, cc1 = 0.f;

    __bf16* hbuf = (role == 0) ? hbuf0 : hbuf1;   // recurrent double buffer
    int* fMy = (role == 0) ? fL0 : (role == 1) ? fX : fL1;

    // xp0 prefetch (role 0 only)
    u32 xc[4] = {0, 0, 0, 0}, xn[4] = {0, 0, 0, 0};
    if (role == 0) {
#pragma unroll
        for (int g = 0; g < 4; g++)
            xc[g] = *(const u32*)(xp0 + (size_t)b * 2048 + g * 512 + j0);
    }

    for (int t = 0; t < 1024; t++) {
        // ---------------- top-of-step wait ----------------
        if (role == 0) {
            int tn = (t < 1023) ? t + 1 : 1023;
#pragma unroll
            for (int g = 0; g < 4; g++)
                xn[g] = *(const u32*)(xp0 + (size_t)(tn * 32 + b) * 2048 + g * 512 + j0);
            if (t > 0) {
                if (tid < 32)
                    while (__hip_atomic_load(&fL0[tid * 1024 + t - 1], __ATOMIC_RELAXED,
                                             SCOPE_AGENT) == 0) {}
                asm volatile("" ::: "memory");
                __syncthreads();
            }
        } else if (role == 1) {
            if (tid < 32)
                while (__hip_atomic_load(&fL0[tid * 1024 + t], __ATOMIC_RELAXED,
                                         SCOPE_AGENT) == 0) {}
            else if (tid == 32 && t >= 4)
                while (__hip_atomic_load(&fL1[w * 1024 + t - 4], __ATOMIC_RELAXED,
                                         SCOPE_AGENT) == 0) {}
            asm volatile("" ::: "memory");
            __syncthreads();
        } else {
            if (tid < 32) {
                if (t > 0)
                    while (__hip_atomic_load(&fL1[tid * 1024 + t - 1], __ATOMIC_RELAXED,
                                             SCOPE_AGENT) == 0) {}
            } else if (tid == 32) {
                while (__hip_atomic_load(&fX[w * 1024 + t], __ATOMIC_RELAXED,
                                         SCOPE_AGENT) == 0) {}
            }
            asm volatile("" ::: "memory");
            __syncthreads();
        }

        // ---------------- stage state into LDS ----------------
        // role0: hbuf0[t&1]; role1: hs0s[t]; role2: xp words + hbuf1[t&1]
        u32 xpr[4];
        if (role == 2) {
            const __bf16* xs = xp1r + (size_t)(t & 3) * 65536 + (size_t)b * 2048 + j0;
#pragma unroll
            for (int g = 0; g < 4; g++)
                xpr[g] = __hip_atomic_load((const u32*)(xs + g * 512),
                                           __ATOMIC_RELAXED, SCOPE_AGENT);
        }
        {
            const u64* hg = (role == 1)
                ? (const u64*)(hs0s + (size_t)t * 16384)
                : (const u64*)(hbuf + (size_t)(t & 1) * 16384);
            u64 hv[16];
#pragma unroll
            for (int i = 0; i < 16; i++)
                hv[i] = __hip_atomic_load(hg + i * 256 + tid, __ATOMIC_RELAXED, SCOPE_AGENT);
#pragma unroll
            for (int i = 0; i < 16; i++) {
                int f  = (i * 256 + tid) * 4;
                int br = f >> 9, col = f & 511;
                *(u64*)(h_lds + br * 516 + col) = hv[i];
            }
        }
        __syncthreads();

        // ---------------- 32 MFMAs ----------------
        f32x4 acc0 = (f32x4){0.f, 0.f, 0.f, 0.f};
        f32x4 acc1 = (f32x4){0.f, 0.f, 0.f, 0.f};
#pragma unroll
        for (int kk = 0; kk < 16; kk++) {
            const __bf16* p0 = h_lds + arow * 516 + kq8 + kk * 32;
            const __bf16* p1 = p0 + 16 * 516;
            bf16x8 a0 = frag_from(*(const u64*)p0, *(const u64*)(p0 + 4));
            bf16x8 a1 = frag_from(*(const u64*)p1, *(const u64*)(p1 + 4));
            acc0 = MFMA16(a0, wreg[kk], acc0);
            acc1 = MFMA16(a1, wreg[kk], acc1);
        }
        {
            int col   = wv * 16 + (lane & 15);
            int rbase = (lane >> 4) * 4;
#pragma unroll
            for (int r = 0; r < 4; r++) {
                g_lds[(rbase + r) * 68 + col]      = acc0[r];
                g_lds[(16 + rbase + r) * 68 + col] = acc1[r];
            }
        }
        __syncthreads();

        // ---------------- per-role epilogue ----------------
        if (role == 1) {
            // pack projection to bf16, store to ring, flag
            const float* gl = g_lds + b * 68 + jp * 2;
            __bf16* xd = xp1r + (size_t)(t & 3) * 65536 + (size_t)b * 2048 + j0;
#pragma unroll
            for (int g = 0; g < 4; g++) {
                f32x2 gv = *(const f32x2*)(gl + g * 16);
                union { __bf16 v2[2]; u32 u; } pu;
                pu.v2[0] = (__bf16)gv[0]; pu.v2[1] = (__bf16)gv[1];
                __hip_atomic_store((u32*)(xd + g * 512), pu.u,
                                   __ATOMIC_RELAXED, SCOPE_AGENT);
            }
            asm volatile("s_waitcnt vmcnt(0)" ::: "memory");
            __syncthreads();
            if (tid == 0)
                __hip_atomic_store(&fX[w * 1024 + t], 1, __ATOMIC_RELAXED, SCOPE_AGENT);
        } else {
            float hf0, hf1;
            {
                u32 x0 = (role == 0) ? xc[0] : xpr[0];
                u32 x1 = (role == 0) ? xc[1] : xpr[1];
                u32 x2 = (role == 0) ? xc[2] : xpr[2];
                u32 x3 = (role == 0) ? xc[3] : xpr[3];
                union { u32 u; __bf16 v2[2]; } xi, xf, xg, xo;
                xi.u = x0; xf.u = x1; xg.u = x2; xo.u = x3;
                const float* gl = g_lds + b * 68 + jp * 2;
                f32x2 gi = *(const f32x2*)(gl);
                f32x2 gf = *(const f32x2*)(gl + 16);
                f32x2 gg = *(const f32x2*)(gl + 32);
                f32x2 go = *(const f32x2*)(gl + 48);

                float i0 = fsigm(gi[0] + (float)xi.v2[0] + bsv[0][0]);
                float f0 = fsigm(gf[0] + (float)xf.v2[0] + bsv[1][0]);
                float g0 = ftanh(gg[0] + (float)xg.v2[0] + bsv[2][0]);
                float o0 = fsigm(go[0] + (float)xo.v2[0] + bsv[3][0]);
                cc0 = f0 * cc0 + i0 * g0;
                hf0 = o0 * ftanh(cc0);

                float i1 = fsigm(gi[1] + (float)xi.v2[1] + bsv[0][1]);
                float f1 = fsigm(gf[1] + (float)xf.v2[1] + bsv[1][1]);
                float g1 = ftanh(gg[1] + (float)xg.v2[1] + bsv[2][1]);
                float o1 = fsigm(go[1] + (float)xo.v2[1] + bsv[3][1]);
                cc1 = f1 * cc1 + i1 * g1;
                hf1 = o1 * ftanh(cc1);
            }
            union { __bf16 v2[2]; u32 u; } hu;
            hu.v2[0] = (__bf16)hf0; hu.v2[1] = (__bf16)hf1;

            // recurrent state store (+ hs0 slot for role 0)
            __hip_atomic_store((u32*)(hbuf + (size_t)((t + 1) & 1) * 16384 +
                                      (size_t)b * 512 + j0),
                               hu.u, __ATOMIC_RELAXED, SCOPE_AGENT);
            if (role == 0)
                __hip_atomic_store((u32*)(hs0s + ((size_t)t * 32 + b) * 512 + j0), hu.u,
                                   __ATOMIC_RELAXED, SCOPE_AGENT);
            asm volatile("s_waitcnt vmcnt(0)" ::: "memory");
            __syncthreads();
            if (tid == 0)
                __hip_atomic_store(&fMy[w * 1024 + t], 1, __ATOMIC_RELAXED, SCOPE_AGENT);

            // non-critical stores overlap flag propagation
            if (role == 2)
                *(f32x2*)(out_f32 + (size_t)b * 524288 + (size_t)t * 512 + j0) =
                    (f32x2){hf0, hf1};
            if (t == 1023) {
                int li = (role == 0) ? 0 : 1;
                *(f32x2*)(hn_out + (size_t)li * 16384 + (size_t)b * 512 + j0) =
                    (f32x2){hf0, hf1};
                *(f32x2*)(cn_out + (size_t)li * 16384 + (size_t)b * 512 + j0) =
                    (f32x2){cc0, cc1};
            }
#pragma unroll
            for (int g = 0; g < 4; g++) xc[g] = xn[g];
        }
    }
}

// ---------------------------------------------------------------------------
extern "C" void kernel_launch(void* const* d_in, const int* in_sizes, int n_in,
                              void* d_out, int out_size, void* d_ws, size_t ws_size,
                              hipStream_t stream) {
    (void)in_sizes; (void)n_in; (void)out_size; (void)ws_size;
    const float* x    = (const float*)d_in[0];  // [32][1024][256] fp32
    const float* Wih0 = (const float*)d_in[1];  // [2048][256] fp32
    const float* b0   = (const float*)d_in[2];  // [2048] fp32
    const float* Whh0 = (const float*)d_in[3];  // [2048][512] fp32
    const float* Wih1 = (const float*)d_in[4];  // [2048][512] fp32
    const float* b1   = (const float*)d_in[5];  // [2048] fp32
    const float* Whh1 = (const float*)d_in[6];  // [2048][512] fp32
    float* dout = (float*)d_out;  // fp32: out(16777216) | h_n(2*16384) | c_n(2*16384)

    char* wsb = (char*)d_ws;
    int*    fL0   = (int*)wsb;                                  // 128 KB
    int*    fX    = (int*)(wsb + (128 << 10));                  // 128 KB
    int*    fL1   = (int*)(wsb + (256 << 10));                  // 128 KB
    __bf16* hbuf0 = (__bf16*)(wsb + (384 << 10));               // 64 KB
    __bf16* hbuf1 = (__bf16*)(wsb + (448 << 10));               // 64 KB
    __bf16* WB0   = (__bf16*)(wsb + (512 << 10));               // 2 MB
    __bf16* WBw1  = (__bf16*)(wsb + (512 << 10) + (2 << 20));   // 2 MB
    __bf16* WBi1  = (__bf16*)(wsb + (512 << 10) + (4 << 20));   // 2 MB
    __bf16* xp1r  = (__bf16*)(wsb + (512 << 10) + (6 << 20));   // 512 KB
    __bf16* hs0s  = (__bf16*)(wsb + (1 << 20) + (7 << 20));     // 32 MB
    __bf16* xpb   = (__bf16*)(wsb + (40 << 20));                // 128 MB

    // zero flags + both h double-buffers (contiguous 512 KB)
    (void)hipMemsetAsync(wsb, 0, 512 << 10, stream);

    pack_w3<<<dim3(1536), dim3(256), 0, stream>>>(Whh0, Whh1, Wih1, WB0, WBw1, WBi1);

    // xp0 = x @ Wih0^T  (K=256, fp32 A, permuted rows)
    gemm_xp<<<dim3(4096), dim3(256), 0, stream>>>(x, Wih0, xpb, 256);

    lstm_pipe3<<<dim3(96), dim3(256), 0, stream>>>(
        xpb, WB0, WBw1, WBi1, b0, b1, hbuf0, hbuf1, hs0s, xp1r,
        dout, dout + 16777216, dout + 16777216 + 32768, fL0, fX, fL1);
}

// Round 9
// 3714.588 us; speedup vs baseline: 1.1241x; 1.0409x over previous
//
#include <hip/hip_runtime.h>

// ---------------------------------------------------------------------------
// 2-layer LSTM, T=1024, B=32, D=256, H=512. Inputs fp32, OUTPUT fp32.
//   pack_w3: fp32 {W_hh0, W_hh1, W_ih1} -> bf16 MFMA B-fragment order.
//   lstm_fused (R15): single persistent kernel, grid 608 x 256:
//     wgs 0..95  : the PROVEN 3-stage recurrence (R0 baseline, byte-identical
//                  protocol): role0 L0, role1 XP1, role2 L1.
//     wgs 96..607: 512 xp0-PRODUCER wgs. Each computes 8 of the 4096 128x128
//                  tiles of xp0 = x @ Wih0^T in bm-major (t-major) order,
//                  stores bf16 pairs via agent atomic u32 (same primitive as
//                  role1's xp1r path), vmcnt(0)+barrier, then agent
//                  atomicAdd(xpcnt[bm],1). Tile bm ready when xpcnt[bm]==16.
//   L0 gates its xp0 reads on xpcnt with its idle tid==32 thread IN PARALLEL
//   with the existing fan-in-32 fL0 poll -> zero critical-path cost in steady
//   state (producers run ~10x faster than L0 consumes). This removes the
//   ~300 us serial gemm_xp phase (total 3866 vs lstm dispatch 3515 us).
//   Deadlock-free: producers depend on nothing; all 608 wgs co-resident
//   (41 KB LDS -> 3 wgs/CU -> 768 slots). Roles 1/2 untouched.
// ---------------------------------------------------------------------------

typedef __bf16 bf16x8 __attribute__((ext_vector_type(8)));
typedef float  f32x4  __attribute__((ext_vector_type(4)));
typedef float  f32x2  __attribute__((ext_vector_type(2)));
typedef unsigned long long u64;
typedef unsigned int u32;

#define MFMA16(a, b, c) __builtin_amdgcn_mfma_f32_16x16x32_bf16((a), (b), (c), 0, 0, 0)
#define SCOPE_AGENT __HIP_MEMORY_SCOPE_AGENT

__device__ __forceinline__ float fsigm(float x) { return 1.0f / (1.0f + __expf(-x)); }
__device__ __forceinline__ float ftanh(float x) {
    x = fminf(15.0f, fmaxf(-15.0f, x));
    float e = __expf(2.0f * x);
    return (e - 1.0f) / (e + 1.0f);
}

__device__ __forceinline__ bf16x8 frag_from(u64 lo, u64 hi) {
    union { u64 u[2]; bf16x8 v; } x;
    x.u[0] = lo; x.u[1] = hi;
    return x.v;
}

// ---------------------------------------------------------------------------
// Pack [2048][512] fp32 -> per-(wg,wave,ktile) bf16 B-fragment order:
//   WB[((w*4+v)*16+kk)*512 + lane*8 + e] = bf16(W[grow][k0+e])
//   n = v*16+(lane&15); grow = (n>>4)*512 + w*16 + (n&15); k0 = kk*32+(lane>>4)*8
// wg w owns h-cols [w*16, w*16+16) for all 4 gates.
// ---------------------------------------------------------------------------
__global__ void pack_w3(const float* __restrict__ W0, const float* __restrict__ W1,
                        const float* __restrict__ W2, __bf16* __restrict__ O0,
                        __bf16* __restrict__ O1, __bf16* __restrict__ O2) {
    int gtid = blockIdx.x * 256 + threadIdx.x;          // 0 .. 393215
    int sel  = gtid >> 17;                              // 0,1,2
    const float* W = (sel == 0) ? W0 : (sel == 1) ? W1 : W2;
    __bf16* WB     = (sel == 0) ? O0 : (sel == 1) ? O1 : O2;
    int tid  = gtid & 131071;
    int lane = tid & 63;
    int kk   = (tid >> 6) & 15;
    int v    = (tid >> 10) & 3;
    int w    = tid >> 12;                               // 0..31
    int n    = v * 16 + (lane & 15);
    int grow = (n >> 4) * 512 + w * 16 + (n & 15);
    int k0   = kk * 32 + (lane >> 4) * 8;
    const float* src = W + (size_t)grow * 512 + k0;
    bf16x8 val;
#pragma unroll
    for (int e = 0; e < 8; e++) val[e] = (__bf16)src[e];
    *(bf16x8*)(WB + (size_t)tid * 8) = val;
}

// ---------------------------------------------------------------------------
// Fused persistent kernel. 608 wgs x 256.
//   blockIdx <  96 : 3-stage recurrence (role = blockIdx/32, w = %32)
//   blockIdx >= 96 : xp0 producer (512 wgs x 8 tiles, bm-major)
// ---------------------------------------------------------------------------
__global__ __launch_bounds__(256, 1) void lstm_fused(
    const float* __restrict__ x,       // [32][1024][256] fp32 (producer input)
    const float* __restrict__ Wih0,    // [2048][256] fp32 (producer input)
    __bf16* __restrict__ xp0,          // [32768][2048] bf16, row = t*32+b
    const __bf16* __restrict__ WB0,    // W_hh0 packed
    const __bf16* __restrict__ WBw1,   // W_hh1 packed
    const __bf16* __restrict__ WBi1,   // W_ih1 packed
    const float* __restrict__ bias0,
    const float* __restrict__ bias1,
    __bf16* __restrict__ hbuf0,        // [2][32][512] zeroed
    __bf16* __restrict__ hbuf1,        // [2][32][512] zeroed
    __bf16* __restrict__ hs0s,         // [1024][32][512] write-once slots
    __bf16* __restrict__ xp1r,         // [4][32][2048] ring
    float* __restrict__ out_f32,       // [32][1024][512]
    float* __restrict__ hn_out,        // [2][32][512]
    float* __restrict__ cn_out,        // [2][32][512]
    int* __restrict__ fL0,             // [32][1024] zeroed, stride 1024
    int* __restrict__ fX,              // [32][1024] zeroed
    int* __restrict__ fL1,             // [32][1024] zeroed
    u32* __restrict__ xpcnt) {         // [256] zeroed, ==16 -> bm tile ready
    const int tid  = threadIdx.x;
    const int lane = tid & 63;
    const int wv   = tid >> 6;

    // =====================================================================
    // xp0 producers (no LDS, no weights-in-reg; pure GEMM tiles)
    // =====================================================================
    if (blockIdx.x >= 96) {
        const int wkr = blockIdx.x - 96;          // 0..511
        const int kq = (lane >> 4) * 8;
        const int rl = lane & 15;
        const int rq = (lane >> 4) * 4;
#pragma unroll 1
        for (int it = 0; it < 8; it++) {
            const int tile = wkr + 512 * it;      // bm-major: early t first
            const int bm = tile >> 4, bn = tile & 15;
            const int m_base = bm * 128 + (wv & 1) * 64;
            const int n_base = bn * 128 + (wv >> 1) * 64;

            f32x4 acc[4][4];
#pragma unroll
            for (int i = 0; i < 4; i++)
#pragma unroll
                for (int j = 0; j < 4; j++) acc[i][j] = (f32x4){0.f, 0.f, 0.f, 0.f};

#pragma unroll 1
            for (int kk = 0; kk < 8; kk++) {      // K = 256
                int k0 = kk * 32 + kq;
                bf16x8 af[4], bfr[4];
#pragma unroll
                for (int mt = 0; mt < 4; mt++) {
                    int row = m_base + mt * 16 + rl;
                    const float* ap = x + (size_t)((row & 31) * 1024 + (row >> 5)) * 256 + k0;
#pragma unroll
                    for (int e = 0; e < 8; e++) af[mt][e] = (__bf16)ap[e];
                }
#pragma unroll
                for (int nt = 0; nt < 4; nt++) {
                    int n = n_base + nt * 16 + rl;
                    const float* wp = Wih0 + (size_t)n * 256 + k0;
#pragma unroll
                    for (int e = 0; e < 8; e++) bfr[nt][e] = (__bf16)wp[e];
                }
#pragma unroll
                for (int mt = 0; mt < 4; mt++)
#pragma unroll
                    for (int nt = 0; nt < 4; nt++)
                        acc[mt][nt] = MFMA16(af[mt], bfr[nt], acc[mt][nt]);
            }

            // paired bf16 stores, agent scope (cross-XCD visible pre-flag)
#pragma unroll
            for (int mt = 0; mt < 4; mt++)
#pragma unroll
                for (int nt = 0; nt < 4; nt++)
#pragma unroll
                    for (int r = 0; r < 4; r++) {
                        float v  = acc[mt][nt][r];
                        float vn = __shfl_down(v, 1);
                        if (!(rl & 1)) {
                            int row = m_base + mt * 16 + rq + r;
                            int col = n_base + nt * 16 + rl;
                            union { __bf16 v2[2]; u32 u; } pu;
                            pu.v2[0] = (__bf16)v; pu.v2[1] = (__bf16)vn;
                            __hip_atomic_store((u32*)(xp0 + (size_t)row * 2048 + col),
                                               pu.u, __ATOMIC_RELAXED, SCOPE_AGENT);
                        }
                    }
            asm volatile("s_waitcnt vmcnt(0)" ::: "memory");
            __syncthreads();
            if (tid == 0)
                __hip_atomic_fetch_add(&xpcnt[bm], 1u, __ATOMIC_RELAXED, SCOPE_AGENT);
        }
        return;
    }

    // =====================================================================
    // The proven 3-stage recurrence (R0 protocol)
    // =====================================================================
    const int role = blockIdx.x >> 5;   // 0=L0, 1=XP1, 2=L1
    const int w    = blockIdx.x & 31;

    __shared__ __bf16 h_lds[32 * 516];  // staged state (stride 516)
    __shared__ float  g_lds[32 * 68];   // gates [32 b][64 cols +4]

    // --- weights resident in registers (64 VGPRs/lane) ---
    bf16x8 wreg[16];
    {
        const __bf16* WB = (role == 0) ? WB0 : (role == 1) ? WBi1 : WBw1;
        const __bf16* wb = WB + (size_t)(w * 4 + wv) * 16 * 512 + lane * 8;
#pragma unroll
        for (int kk = 0; kk < 16; kk++) wreg[kk] = *(const bf16x8*)(wb + kk * 512);
    }

    // --- elementwise mapping: thread -> (b, j0, j0+1) ---
    const int b  = tid >> 3;
    const int jp = tid & 7;
    const int j0 = w * 16 + jp * 2;
    const int arow = lane & 15;
    const int kq8  = (lane >> 4) * 8;

    f32x2 bsv[4];
    if (role != 1) {
        const float* bias = (role == 0) ? bias0 : bias1;
#pragma unroll
        for (int g = 0; g < 4; g++) bsv[g] = *(const f32x2*)(bias + g * 512 + j0);
    }
    float cc0 = 0.f, cc1 = 0.f;

    __bf16* hbuf = (role == 0) ? hbuf0 : hbuf1;   // recurrent double buffer
    int* fMy = (role == 0) ? fL0 : (role == 1) ? fX : fL1;

    // xp0 prefetch (role 0 only) — gated on producer tile 0
    u32 xc[4] = {0, 0, 0, 0}, xn[4] = {0, 0, 0, 0};
    if (role == 0) {
        if (tid == 32)
            while (__hip_atomic_load(&xpcnt[0], __ATOMIC_RELAXED, SCOPE_AGENT) < 16u) {}
        asm volatile("" ::: "memory");
        __syncthreads();
#pragma unroll
        for (int g = 0; g < 4; g++)
            xc[g] = __hip_atomic_load((const u32*)(xp0 + (size_t)b * 2048 + g * 512 + j0),
                                      __ATOMIC_RELAXED, SCOPE_AGENT);
    }

    for (int t = 0; t < 1024; t++) {
        // ---------------- top-of-step wait ----------------
        if (role == 0) {
            int tn = (t < 1023) ? t + 1 : 1023;
            // fan-in-32 peer poll (tid<32) || producer-tile gate (tid==32),
            // concurrent threads -> no added serial latency in steady state
            if (t > 0) {
                if (tid < 32)
                    while (__hip_atomic_load(&fL0[tid * 1024 + t - 1], __ATOMIC_RELAXED,
                                             SCOPE_AGENT) == 0) {}
            }
            if (tid == 32)
                while (__hip_atomic_load(&xpcnt[tn >> 2], __ATOMIC_RELAXED,
                                         SCOPE_AGENT) < 16u) {}
            asm volatile("" ::: "memory");
            __syncthreads();
            // xn loads after the gate (consumed next step; latency hidden)
#pragma unroll
            for (int g = 0; g < 4; g++)
                xn[g] = __hip_atomic_load(
                    (const u32*)(xp0 + (size_t)(tn * 32 + b) * 2048 + g * 512 + j0),
                    __ATOMIC_RELAXED, SCOPE_AGENT);
        } else if (role == 1) {
            if (tid < 32)
                while (__hip_atomic_load(&fL0[tid * 1024 + t], __ATOMIC_RELAXED,
                                         SCOPE_AGENT) == 0) {}
            else if (tid == 32 && t >= 4)
                while (__hip_atomic_load(&fL1[w * 1024 + t - 4], __ATOMIC_RELAXED,
                                         SCOPE_AGENT) == 0) {}
            asm volatile("" ::: "memory");
            __syncthreads();
        } else {
            if (tid < 32) {
                if (t > 0)
                    while (__hip_atomic_load(&fL1[tid * 1024 + t - 1], __ATOMIC_RELAXED,
                                             SCOPE_AGENT) == 0) {}
            } else if (tid == 32) {
                while (__hip_atomic_load(&fX[w * 1024 + t], __ATOMIC_RELAXED,
                                         SCOPE_AGENT) == 0) {}
            }
            asm volatile("" ::: "memory");
            __syncthreads();
        }

        // ---------------- stage state into LDS ----------------
        // role0: hbuf0[t&1]; role1: hs0s[t]; role2: xp words + hbuf1[t&1]
        u32 xpr[4];
        if (role == 2) {
            const __bf16* xs = xp1r + (size_t)(t & 3) * 65536 + (size_t)b * 2048 + j0;
#pragma unroll
            for (int g = 0; g < 4; g++)
                xpr[g] = __hip_atomic_load((const u32*)(xs + g * 512),
                                           __ATOMIC_RELAXED, SCOPE_AGENT);
        }
        {
            const u64* hg = (role == 1)
                ? (const u64*)(hs0s + (size_t)t * 16384)
                : (const u64*)(hbuf + (size_t)(t & 1) * 16384);
            u64 hv[16];
#pragma unroll
            for (int i = 0; i < 16; i++)
                hv[i] = __hip_atomic_load(hg + i * 256 + tid, __ATOMIC_RELAXED, SCOPE_AGENT);
#pragma unroll
            for (int i = 0; i < 16; i++) {
                int f  = (i * 256 + tid) * 4;
                int br = f >> 9, col = f & 511;
                *(u64*)(h_lds + br * 516 + col) = hv[i];
            }
        }
        __syncthreads();

        // ---------------- 32 MFMAs ----------------
        f32x4 acc0 = (f32x4){0.f, 0.f, 0.f, 0.f};
        f32x4 acc1 = (f32x4){0.f, 0.f, 0.f, 0.f};
#pragma unroll
        for (int kk = 0; kk < 16; kk++) {
            const __bf16* p0 = h_lds + arow * 516 + kq8 + kk * 32;
            const __bf16* p1 = p0 + 16 * 516;
            bf16x8 a0 = frag_from(*(const u64*)p0, *(const u64*)(p0 + 4));
            bf16x8 a1 = frag_from(*(const u64*)p1, *(const u64*)(p1 + 4));
            acc0 = MFMA16(a0, wreg[kk], acc0);
            acc1 = MFMA16(a1, wreg[kk], acc1);
        }
        {
            int col   = wv * 16 + (lane & 15);
            int rbase = (lane >> 4) * 4;
#pragma unroll
            for (int r = 0; r < 4; r++) {
                g_lds[(rbase + r) * 68 + col]      = acc0[r];
                g_lds[(16 + rbase + r) * 68 + col] = acc1[r];
            }
        }
        __syncthreads();

        // ---------------- per-role epilogue ----------------
        if (role == 1) {
            // pack projection to bf16, store to ring, flag
            const float* gl = g_lds + b * 68 + jp * 2;
            __bf16* xd = xp1r + (size_t)(t & 3) * 65536 + (size_t)b * 2048 + j0;
#pragma unroll
            for (int g = 0; g < 4; g++) {
                f32x2 gv = *(const f32x2*)(gl + g * 16);
                union { __bf16 v2[2]; u32 u; } pu;
                pu.v2[0] = (__bf16)gv[0]; pu.v2[1] = (__bf16)gv[1];
                __hip_atomic_store((u32*)(xd + g * 512), pu.u,
                                   __ATOMIC_RELAXED, SCOPE_AGENT);
            }
            asm volatile("s_waitcnt vmcnt(0)" ::: "memory");
            __syncthreads();
            if (tid == 0)
                __hip_atomic_store(&fX[w * 1024 + t], 1, __ATOMIC_RELAXED, SCOPE_AGENT);
        } else {
            float hf0, hf1;
            {
                u32 x0 = (role == 0) ? xc[0] : xpr[0];
                u32 x1 = (role == 0) ? xc[1] : xpr[1];
                u32 x2 = (role == 0) ? xc[2] : xpr[2];
                u32 x3 = (role == 0) ? xc[3] : xpr[3];
                union { u32 u; __bf16 v2[2]; } xi, xf, xg, xo;
                xi.u = x0; xf.u = x1; xg.u = x2; xo.u = x3;
                const float* gl = g_lds + b * 68 + jp * 2;
                f32x2 gi = *(const f32x2*)(gl);
                f32x2 gf = *(const f32x2*)(gl + 16);
                f32x2 gg = *(const f32x2*)(gl + 32);
                f32x2 go = *(const f32x2*)(gl + 48);

                float i0 = fsigm(gi[0] + (float)xi.v2[0] + bsv[0][0]);
                float f0 = fsigm(gf[0] + (float)xf.v2[0] + bsv[1][0]);
                float g0 = ftanh(gg[0] + (float)xg.v2[0] + bsv[2][0]);
                float o0 = fsigm(go[0] + (float)xo.v2[0] + bsv[3][0]);
                cc0 = f0 * cc0 + i0 * g0;
                hf0 = o0 * ftanh(cc0);

                float i1 = fsigm(gi[1] + (float)xi.v2[1] + bsv[0][1]);
                float f1 = fsigm(gf[1] + (float)xf.v2[1] + bsv[1][1]);
                float g1 = ftanh(gg[1] + (float)xg.v2[1] + bsv[2][1]);
                float o1 = fsigm(go[1] + (float)xo.v2[1] + bsv[3][1]);
                cc1 = f1 * cc1 + i1 * g1;
                hf1 = o1 * ftanh(cc1);
            }
            union { __bf16 v2[2]; u32 u; } hu;
            hu.v2[0] = (__bf16)hf0; hu.v2[1] = (__bf16)hf1;

            // recurrent state store (+ hs0 slot for role 0)
            __hip_atomic_store((u32*)(hbuf + (size_t)((t + 1) & 1) * 16384 +
                                      (size_t)b * 512 + j0),
                               hu.u, __ATOMIC_RELAXED, SCOPE_AGENT);
            if (role == 0)
                __hip_atomic_store((u32*)(hs0s + ((size_t)t * 32 + b) * 512 + j0), hu.u,
                                   __ATOMIC_RELAXED, SCOPE_AGENT);
            asm volatile("s_waitcnt vmcnt(0)" ::: "memory");
            __syncthreads();
            if (tid == 0)
                __hip_atomic_store(&fMy[w * 1024 + t], 1, __ATOMIC_RELAXED, SCOPE_AGENT);

            // non-critical stores overlap flag propagation
            if (role == 2)
                *(f32x2*)(out_f32 + (size_t)b * 524288 + (size_t)t * 512 + j0) =
                    (f32x2){hf0, hf1};
            if (t == 1023) {
                int li = (role == 0) ? 0 : 1;
                *(f32x2*)(hn_out + (size_t)li * 16384 + (size_t)b * 512 + j0) =
                    (f32x2){hf0, hf1};
                *(f32x2*)(cn_out + (size_t)li * 16384 + (size_t)b * 512 + j0) =
                    (f32x2){cc0, cc1};
            }
#pragma unroll
            for (int g = 0; g < 4; g++) xc[g] = xn[g];
        }
    }
}

// ---------------------------------------------------------------------------
extern "C" void kernel_launch(void* const* d_in, const int* in_sizes, int n_in,
                              void* d_out, int out_size, void* d_ws, size_t ws_size,
                              hipStream_t stream) {
    (void)in_sizes; (void)n_in; (void)out_size; (void)ws_size;
    const float* x    = (const float*)d_in[0];  // [32][1024][256] fp32
    const float* Wih0 = (const float*)d_in[1];  // [2048][256] fp32
    const float* b0   = (const float*)d_in[2];  // [2048] fp32
    const float* Whh0 = (const float*)d_in[3];  // [2048][512] fp32
    const float* Wih1 = (const float*)d_in[4];  // [2048][512] fp32
    const float* b1   = (const float*)d_in[5];  // [2048] fp32
    const float* Whh1 = (const float*)d_in[6];  // [2048][512] fp32
    float* dout = (float*)d_out;  // fp32: out(16777216) | h_n(2*16384) | c_n(2*16384)

    char* wsb = (char*)d_ws;
    int*    fL0   = (int*)wsb;                                  // 128 KB
    int*    fX    = (int*)(wsb + (128 << 10));                  // 128 KB
    int*    fL1   = (int*)(wsb + (256 << 10));                  // 128 KB
    __bf16* hbuf0 = (__bf16*)(wsb + (384 << 10));               // 64 KB
    __bf16* hbuf1 = (__bf16*)(wsb + (448 << 10));               // 64 KB
    u32*    xpcnt = (u32*)(wsb + (512 << 10));                  // 4 KB (256 cnt)
    __bf16* WB0   = (__bf16*)(wsb + (516 << 10));               // 2 MB
    __bf16* WBw1  = (__bf16*)(wsb + (516 << 10) + (2 << 20));   // 2 MB
    __bf16* WBi1  = (__bf16*)(wsb + (516 << 10) + (4 << 20));   // 2 MB
    __bf16* xp1r  = (__bf16*)(wsb + (516 << 10) + (6 << 20));   // 512 KB
    __bf16* hs0s  = (__bf16*)(wsb + (8 << 20));                 // 32 MB
    __bf16* xpb   = (__bf16*)(wsb + (40 << 20));                // 128 MB

    // zero flags + h double-buffers + xpcnt (contiguous 516 KB)
    (void)hipMemsetAsync(wsb, 0, 516 << 10, stream);

    pack_w3<<<dim3(1536), dim3(256), 0, stream>>>(Whh0, Whh1, Wih1, WB0, WBw1, WBi1);

    // single fused launch: 96 recurrence wgs + 512 xp0 producers
    lstm_fused<<<dim3(608), dim3(256), 0, stream>>>(
        x, Wih0, xpb, WB0, WBw1, WBi1, b0, b1, hbuf0, hbuf1, hs0s, xp1r,
        dout, dout + 16777216, dout + 16777216 + 32768, fL0, fX, fL1, xpcnt);
}